// Round 1
// baseline (2118.759 us; speedup 1.0000x reference)
//
#include <hip/hip_runtime.h>

#define N_PTS 65536
#define H 256
#define P 8          // points per workgroup
#define NTHREADS 256

__device__ __constant__ float NU_C = 0.0031830988618379067f; // 0.01/pi in fp32

// Streams: 0=value, 1=d/dt, 2=d/dx, 3=d/dy, 4=d2/dx2, 5=d2/dy2
__global__ __launch_bounds__(NTHREADS)
void pinn_burger2d_kernel(
    const float* __restrict__ t, const float* __restrict__ x, const float* __restrict__ y,
    const float* __restrict__ W0, const float* __restrict__ b0,
    const float* __restrict__ W1, const float* __restrict__ b1,
    const float* __restrict__ W2, const float* __restrict__ b2,
    const float* __restrict__ W3, const float* __restrict__ b3,
    const float* __restrict__ W4, const float* __restrict__ b4,
    float* __restrict__ out)
{
    __shared__ float buf[6][P][H];   // 48 KiB
    __shared__ float res[6][P];

    const int tid  = threadIdx.x;
    const int col  = tid & 127;      // this thread owns columns col and col+128
    const int ph   = tid >> 7;       // point-half: 0 -> points 0..3, 1 -> points 4..7
    const int base = blockIdx.x * P;

    // ---------------- layer 0: (t,x,y) -> 256, tanh jet ----------------
    {
        float tw[2], xw[2], yw[2], bw[2];
        const int cols[2] = {col, col + 128};
        #pragma unroll
        for (int c = 0; c < 2; ++c) {
            tw[c] = W0[0 * H + cols[c]];
            xw[c] = W0[1 * H + cols[c]];
            yw[c] = W0[2 * H + cols[c]];
            bw[c] = b0[cols[c]];
        }
        #pragma unroll
        for (int p = 0; p < 4; ++p) {
            const int pp = ph * 4 + p;
            const int gi = base + pp;
            const float tv = t[gi], xv = x[gi], yv = y[gi];
            #pragma unroll
            for (int c = 0; c < 2; ++c) {
                const float z  = tv * tw[c] + xv * xw[c] + yv * yw[c] + bw[c];
                const float zt = tw[c], zx = xw[c], zy = yw[c];
                const float a  = tanhf(z);
                const float ap = 1.0f - a * a;      // tanh'
                const float am = -2.0f * a * ap;    // tanh''
                buf[0][pp][cols[c]] = a;
                buf[1][pp][cols[c]] = ap * zt;
                buf[2][pp][cols[c]] = ap * zx;
                buf[3][pp][cols[c]] = ap * zy;
                buf[4][pp][cols[c]] = am * zx * zx;  // zxx = 0 at layer 0
                buf[5][pp][cols[c]] = am * zy * zy;  // zyy = 0 at layer 0
            }
        }
    }
    __syncthreads();

    // ---------------- layers 1..3: 256 -> 256, tanh jet ----------------
    const float* Ws[3] = {W1, W2, W3};
    const float* bs[3] = {b1, b2, b3};

    for (int l = 0; l < 3; ++l) {
        const float* __restrict__ W = Ws[l];
        const float* __restrict__ b = bs[l];

        float acc[6][4][2];
        const float bc0 = b[col], bc1 = b[col + 128];
        #pragma unroll
        for (int s = 0; s < 6; ++s)
            #pragma unroll
            for (int p = 0; p < 4; ++p) {
                acc[s][p][0] = (s == 0) ? bc0 : 0.0f;
                acc[s][p][1] = (s == 0) ? bc1 : 0.0f;
            }

        for (int k = 0; k < H; k += 4) {
            float wa[4], wb[4];
            #pragma unroll
            for (int i = 0; i < 4; ++i) {
                wa[i] = W[(k + i) * H + col];
                wb[i] = W[(k + i) * H + col + 128];
            }
            #pragma unroll
            for (int s = 0; s < 6; ++s) {
                #pragma unroll
                for (int p = 0; p < 4; ++p) {
                    const float4 h4 = *(const float4*)&buf[s][ph * 4 + p][k];
                    acc[s][p][0] += h4.x * wa[0] + h4.y * wa[1] + h4.z * wa[2] + h4.w * wa[3];
                    acc[s][p][1] += h4.x * wb[0] + h4.y * wb[1] + h4.z * wb[2] + h4.w * wb[3];
                }
            }
        }
        __syncthreads();   // all reads of buf complete before overwrite

        #pragma unroll
        for (int p = 0; p < 4; ++p) {
            const int pp = ph * 4 + p;
            #pragma unroll
            for (int c = 0; c < 2; ++c) {
                const int jc = (c == 0) ? col : col + 128;
                const float z   = acc[0][p][c];
                const float zt  = acc[1][p][c];
                const float zx  = acc[2][p][c];
                const float zy  = acc[3][p][c];
                const float zxx = acc[4][p][c];
                const float zyy = acc[5][p][c];
                const float a  = tanhf(z);
                const float ap = 1.0f - a * a;
                const float am = -2.0f * a * ap;
                buf[0][pp][jc] = a;
                buf[1][pp][jc] = ap * zt;
                buf[2][pp][jc] = ap * zx;
                buf[3][pp][jc] = ap * zy;
                buf[4][pp][jc] = ap * zxx + am * zx * zx;
                buf[5][pp][jc] = ap * zyy + am * zy * zy;
            }
        }
        __syncthreads();
    }

    // ---------------- final layer: 256 -> 1, 48 reductions ----------------
    {
        const int wave = tid >> 6;
        const int lane = tid & 63;
        const float4 w4 = *(const float4*)&W4[lane * 4];
        for (int task = wave; task < 48; task += 4) {
            const int s = task >> 3;
            const int p = task & 7;
            const float4 h4 = *(const float4*)&buf[s][p][lane * 4];
            float part = h4.x * w4.x + h4.y * w4.y + h4.z * w4.z + h4.w * w4.w;
            #pragma unroll
            for (int off = 32; off; off >>= 1) part += __shfl_down(part, off);
            if (lane == 0) res[s][p] = part;
        }
    }
    __syncthreads();

    if (tid < P) {
        const int p  = tid;
        const int gi = base + p;
        const float u   = res[0][p] + b4[0];
        const float ut  = res[1][p];
        const float ux  = res[2][p];
        const float uy  = res[3][p];
        const float uxx = res[4][p];
        const float uyy = res[5][p];
        out[gi]         = u;
        out[N_PTS + gi] = ut + u * ux + u * uy - NU_C * (uxx + uyy);
    }
}

extern "C" void kernel_launch(void* const* d_in, const int* in_sizes, int n_in,
                              void* d_out, int out_size, void* d_ws, size_t ws_size,
                              hipStream_t stream) {
    const float* t  = (const float*)d_in[0];
    const float* x  = (const float*)d_in[1];
    const float* y  = (const float*)d_in[2];
    const float* W0 = (const float*)d_in[3];
    const float* b0 = (const float*)d_in[4];
    const float* W1 = (const float*)d_in[5];
    const float* b1 = (const float*)d_in[6];
    const float* W2 = (const float*)d_in[7];
    const float* b2 = (const float*)d_in[8];
    const float* W3 = (const float*)d_in[9];
    const float* b3 = (const float*)d_in[10];
    const float* W4 = (const float*)d_in[11];
    const float* b4 = (const float*)d_in[12];
    float* out = (float*)d_out;

    pinn_burger2d_kernel<<<N_PTS / P, NTHREADS, 0, stream>>>(
        t, x, y, W0, b0, W1, b1, W2, b2, W3, b3, W4, b4, out);
}

// Round 2
// 739.253 us; speedup vs baseline: 2.8661x; 2.8661x over previous
//
#include <hip/hip_runtime.h>

#define NPTS 65536
#define NU_F 0.0031830988618379067f

typedef __attribute__((ext_vector_type(8))) short short8v;   // 8 bf16 (4 VGPRs)
typedef __attribute__((ext_vector_type(4))) float float4v;   // MFMA C/D

__device__ __forceinline__ ushort f2bf(float f) {
    union { float f; unsigned u; } v; v.f = f;
    return (ushort)((v.u + 0x7FFFu + ((v.u >> 16) & 1u)) >> 16);   // RNE
}
__device__ __forceinline__ float bf2f(ushort b) {
    union { unsigned u; float f; } v; v.u = ((unsigned)b) << 16;
    return v.f;
}

// tanh jet: a, a'=1-a^2, a''=-2a·a'
__device__ __forceinline__ void jet(float z, float zt, float zx, float zy,
                                    float zxx, float zyy,
                                    float& s0, float& s1, float& s2,
                                    float& s3, float& s4, float& s5) {
    float e  = __expf(2.0f * z);
    float a  = 1.0f - 2.0f * __builtin_amdgcn_rcpf(e + 1.0f);
    float ap = 1.0f - a * a;
    float am = -2.0f * a * ap;
    s0 = a;
    s1 = ap * zt;
    s2 = ap * zx;
    s3 = ap * zy;
    s4 = ap * zxx + am * zx * zx;
    s5 = ap * zyy + am * zy * zy;
}

// ---- LDS jet-matrix access, XOR-swizzled: byte ^= ((sp&7)<<4) ----
__device__ __forceinline__ short8v loadB(const char* baseB, int sp, int k2) {
    return *(const short8v*)(baseB + (((sp << 9) + k2) ^ ((sp & 7) << 4)));
}
__device__ __forceinline__ void storeB(char* baseB, int sp, int jb,
                                       ushort a0, ushort a1, ushort a2, ushort a3) {
    ushort4 v = make_ushort4(a0, a1, a2, a3);
    *(ushort4*)(baseB + (((sp << 9) + (jb << 1)) ^ ((sp & 7) << 4))) = v;
}

// ================= prep: W1..W3 -> bf16 hi/lo in A-fragment order =================
// A-frag for mfma_f32_16x16x32_bf16: lane 16g+r holds A[row r][k = 8g + jj], jj=0..7.
// Amat = W^T (row=j output col, k=input). Frag idx = ((M*8 + kt)*64 + lane).
__global__ __launch_bounds__(256)
void pinn_prep_kernel(const float* __restrict__ W1, const float* __restrict__ W2,
                      const float* __restrict__ W3, ushort* __restrict__ ws) {
    int gid  = blockIdx.x * 256 + threadIdx.x;  // 0..24575
    int l    = gid >> 13;                       // layer 0..2 (8192 threads each)
    int rem  = gid & 8191;
    int M    = rem >> 9;                        // 0..15
    int kt   = (rem >> 6) & 7;                  // 0..7
    int lane = rem & 63;
    const float* W = (l == 0) ? W1 : (l == 1) ? W2 : W3;
    int j  = M * 16 + (lane & 15);
    int k0 = kt * 32 + (lane >> 4) * 8;
    union { ushort u[8]; short8v v; } hi, lo;
    #pragma unroll
    for (int jj = 0; jj < 8; ++jj) {
        float v  = W[(k0 + jj) * 256 + j];      // W[k][j] row-major
        ushort h = f2bf(v);
        hi.u[jj] = h;
        lo.u[jj] = f2bf(v - bf2f(h));
    }
    int off = l * 8192 + ((M * 8 + kt) * 64 + lane);
    ((short8v*)ws)[off]         = hi.v;         // hi frags: [0, 24576)
    ((short8v*)ws)[24576 + off] = lo.v;         // lo frags: [24576, 49152)
}

// ================= main kernel: 16 points / block, 256 threads =================
__global__ __launch_bounds__(256, 2)
void pinn_burger2d_kernel(
    const float* __restrict__ t, const float* __restrict__ x, const float* __restrict__ y,
    const float* __restrict__ W0, const float* __restrict__ b0,
    const float* __restrict__ b1, const float* __restrict__ b2, const float* __restrict__ b3,
    const float* __restrict__ W4, const float* __restrict__ b4,
    const ushort* __restrict__ wf, float* __restrict__ out)
{
    // Jet matrix (B operand, stored as Ajet[sp][k] bf16): hi 96 rows, lo 64 rows (streams 0-3)
    __shared__ ushort BhiS[96 * 256];   // 48 KiB
    __shared__ ushort BloS[64 * 256];   // 32 KiB
    char* bhiB = (char*)BhiS;
    char* bloB = (char*)BloS;

    const int tid  = threadIdx.x;
    const int lane = tid & 63;
    const int wv   = tid >> 6;      // wave 0..3, owns j in [wv*64, wv*64+64)
    const int p    = lane & 15;     // point 0..15
    const int rg   = lane >> 4;     // 0..3
    const int base = blockIdx.x * 16;
    const int gi   = base + p;

    const float tv = t[gi], xv = x[gi], yv = y[gi];

    // ---------------- layer 0: (t,x,y) -> 256 jet, write to LDS ----------------
    #pragma unroll
    for (int m = 0; m < 4; ++m) {
        const int jb = wv * 64 + m * 16 + rg * 4;
        float4 w0t = *(const float4*)(W0 + jb);
        float4 w0x = *(const float4*)(W0 + 256 + jb);
        float4 w0y = *(const float4*)(W0 + 512 + jb);
        float4 bb  = *(const float4*)(b0 + jb);
        float wtA[4] = {w0t.x, w0t.y, w0t.z, w0t.w};
        float wxA[4] = {w0x.x, w0x.y, w0x.z, w0x.w};
        float wyA[4] = {w0y.x, w0y.y, w0y.z, w0y.w};
        float bbA[4] = {bb.x, bb.y, bb.z, bb.w};
        ushort h[6][4]; ushort lo[4][4];
        #pragma unroll
        for (int r = 0; r < 4; ++r) {
            float z = tv * wtA[r] + xv * wxA[r] + yv * wyA[r] + bbA[r];
            float s0, s1, s2, s3, s4, s5;
            jet(z, wtA[r], wxA[r], wyA[r], 0.0f, 0.0f, s0, s1, s2, s3, s4, s5);
            float ss[6] = {s0, s1, s2, s3, s4, s5};
            #pragma unroll
            for (int s = 0; s < 6; ++s) {
                h[s][r] = f2bf(ss[s]);
                if (s < 4) lo[s][r] = f2bf(ss[s] - bf2f(h[s][r]));
            }
        }
        #pragma unroll
        for (int s = 0; s < 6; ++s)
            storeB(bhiB, s * 16 + p, jb, h[s][0], h[s][1], h[s][2], h[s][3]);
        #pragma unroll
        for (int s = 0; s < 4; ++s)
            storeB(bloB, s * 16 + p, jb, lo[s][0], lo[s][1], lo[s][2], lo[s][3]);
    }
    __syncthreads();

    float4v acc[4][6];

    // ---------------- layers 1..3: MFMA  Z^T = W^T · Ajet^T ----------------
    for (int li = 0; li < 3; ++li) {
        #pragma unroll
        for (int m = 0; m < 4; ++m)
            #pragma unroll
            for (int n = 0; n < 6; ++n) {
                float4v z4 = {0.0f, 0.0f, 0.0f, 0.0f};
                acc[m][n] = z4;
            }

        const short8v* whf = (const short8v*)wf + li * 8192;
        const short8v* wlf = (const short8v*)wf + 24576 + li * 8192;

        for (int kt = 0; kt < 8; ++kt) {
            short8v bh[6], bl[4];
            const int k2 = kt * 64 + rg * 16;
            #pragma unroll
            for (int n = 0; n < 6; ++n) bh[n] = loadB(bhiB, n * 16 + p, k2);
            #pragma unroll
            for (int n = 0; n < 4; ++n) bl[n] = loadB(bloB, n * 16 + p, k2);
            #pragma unroll
            for (int m = 0; m < 4; ++m) {
                const int fi = ((wv * 4 + m) * 8 + kt) * 64 + lane;
                short8v wh = whf[fi];
                short8v wl = wlf[fi];
                #pragma unroll
                for (int n = 0; n < 6; ++n)
                    acc[m][n] = __builtin_amdgcn_mfma_f32_16x16x32_bf16(wh, bh[n], acc[m][n], 0, 0, 0);
                #pragma unroll
                for (int n = 0; n < 4; ++n)
                    acc[m][n] = __builtin_amdgcn_mfma_f32_16x16x32_bf16(wl, bh[n], acc[m][n], 0, 0, 0);
                #pragma unroll
                for (int n = 0; n < 4; ++n)
                    acc[m][n] = __builtin_amdgcn_mfma_f32_16x16x32_bf16(wh, bl[n], acc[m][n], 0, 0, 0);
            }
        }
        __syncthreads();   // all waves done reading B before overwrite / reuse

        if (li < 2) {
            const float* bL = (li == 0) ? b1 : b2;
            #pragma unroll
            for (int m = 0; m < 4; ++m) {
                const int jb = wv * 64 + m * 16 + rg * 4;
                float4 bb = *(const float4*)(bL + jb);
                float bbA[4] = {bb.x, bb.y, bb.z, bb.w};
                ushort h[6][4]; ushort lo[4][4];
                #pragma unroll
                for (int r = 0; r < 4; ++r) {
                    float z   = acc[m][0][r] + bbA[r];
                    float s0, s1, s2, s3, s4, s5;
                    jet(z, acc[m][1][r], acc[m][2][r], acc[m][3][r],
                        acc[m][4][r], acc[m][5][r], s0, s1, s2, s3, s4, s5);
                    float ss[6] = {s0, s1, s2, s3, s4, s5};
                    #pragma unroll
                    for (int s = 0; s < 6; ++s) {
                        h[s][r] = f2bf(ss[s]);
                        if (s < 4) lo[s][r] = f2bf(ss[s] - bf2f(h[s][r]));
                    }
                }
                #pragma unroll
                for (int s = 0; s < 6; ++s)
                    storeB(bhiB, s * 16 + p, jb, h[s][0], h[s][1], h[s][2], h[s][3]);
                #pragma unroll
                for (int s = 0; s < 4; ++s)
                    storeB(bloB, s * 16 + p, jb, lo[s][0], lo[s][1], lo[s][2], lo[s][3]);
            }
            __syncthreads();
        }
    }

    // ---------------- layer-3 jet (registers) + final 256->1 dot ----------------
    float part[6] = {0, 0, 0, 0, 0, 0};
    #pragma unroll
    for (int m = 0; m < 4; ++m) {
        const int jb = wv * 64 + m * 16 + rg * 4;
        float4 bb = *(const float4*)(b3 + jb);
        float4 w4 = *(const float4*)(W4 + jb);
        float bbA[4] = {bb.x, bb.y, bb.z, bb.w};
        float w4A[4] = {w4.x, w4.y, w4.z, w4.w};
        #pragma unroll
        for (int r = 0; r < 4; ++r) {
            float z = acc[m][0][r] + bbA[r];
            float s0, s1, s2, s3, s4, s5;
            jet(z, acc[m][1][r], acc[m][2][r], acc[m][3][r],
                acc[m][4][r], acc[m][5][r], s0, s1, s2, s3, s4, s5);
            part[0] += s0 * w4A[r];
            part[1] += s1 * w4A[r];
            part[2] += s2 * w4A[r];
            part[3] += s3 * w4A[r];
            part[4] += s4 * w4A[r];
            part[5] += s5 * w4A[r];
        }
    }
    // reduce over the 4 lanes sharing a point (lane, lane^16, lane^32, lane^48)
    #pragma unroll
    for (int s = 0; s < 6; ++s) {
        part[s] += __shfl_xor(part[s], 16, 64);
        part[s] += __shfl_xor(part[s], 32, 64);
    }
    float* resf = (float*)BloS;   // overlay (Blo no longer needed; barrier above protects)
    if (lane < 16) {
        #pragma unroll
        for (int s = 0; s < 6; ++s) resf[(wv * 6 + s) * 16 + p] = part[s];
    }
    __syncthreads();

    if (tid < 16) {
        const int pp = tid;
        const int g  = base + pp;
        float u = b4[0], ut = 0, ux = 0, uy = 0, uxx = 0, uyy = 0;
        #pragma unroll
        for (int w = 0; w < 4; ++w) {
            u   += resf[(w * 6 + 0) * 16 + pp];
            ut  += resf[(w * 6 + 1) * 16 + pp];
            ux  += resf[(w * 6 + 2) * 16 + pp];
            uy  += resf[(w * 6 + 3) * 16 + pp];
            uxx += resf[(w * 6 + 4) * 16 + pp];
            uyy += resf[(w * 6 + 5) * 16 + pp];
        }
        out[g]        = u;
        out[NPTS + g] = ut + u * ux + u * uy - NU_F * (uxx + uyy);
    }
}

extern "C" void kernel_launch(void* const* d_in, const int* in_sizes, int n_in,
                              void* d_out, int out_size, void* d_ws, size_t ws_size,
                              hipStream_t stream) {
    const float* t  = (const float*)d_in[0];
    const float* x  = (const float*)d_in[1];
    const float* y  = (const float*)d_in[2];
    const float* W0 = (const float*)d_in[3];
    const float* b0 = (const float*)d_in[4];
    const float* W1 = (const float*)d_in[5];
    const float* b1 = (const float*)d_in[6];
    const float* W2 = (const float*)d_in[7];
    const float* b2 = (const float*)d_in[8];
    const float* W3 = (const float*)d_in[9];
    const float* b3 = (const float*)d_in[10];
    const float* W4 = (const float*)d_in[11];
    const float* b4 = (const float*)d_in[12];
    float* out = (float*)d_out;

    pinn_prep_kernel<<<96, 256, 0, stream>>>(W1, W2, W3, (ushort*)d_ws);
    pinn_burger2d_kernel<<<NPTS / 16, 256, 0, stream>>>(
        t, x, y, W0, b0, b1, b2, b3, W4, b4, (const ushort*)d_ws, out);
}

// Round 3
// 491.299 us; speedup vs baseline: 4.3126x; 1.5047x over previous
//
#include <hip/hip_runtime.h>

#define NPTS 65536
#define NU_F 0.0031830988618379067f

typedef __attribute__((ext_vector_type(8))) short short8v;   // 8 bf16 (4 VGPRs)
typedef __attribute__((ext_vector_type(4))) float float4v;   // MFMA C/D

__device__ __forceinline__ ushort f2bf(float f) {
    union { float f; unsigned u; } v; v.f = f;
    return (ushort)((v.u + 0x7FFFu + ((v.u >> 16) & 1u)) >> 16);   // RNE
}
__device__ __forceinline__ float bf2f(ushort b) {
    union { unsigned u; float f; } v; v.u = ((unsigned)b) << 16;
    return v.f;
}

// tanh jet: a, a'=1-a^2, a''=-2a·a'
__device__ __forceinline__ void jet(float z, float zt, float zx, float zy,
                                    float zxx, float zyy,
                                    float& s0, float& s1, float& s2,
                                    float& s3, float& s4, float& s5) {
    float e  = __expf(2.0f * z);
    float a  = 1.0f - 2.0f * __builtin_amdgcn_rcpf(e + 1.0f);
    float ap = 1.0f - a * a;
    float am = -2.0f * a * ap;
    s0 = a;
    s1 = ap * zt;
    s2 = ap * zx;
    s3 = ap * zy;
    s4 = ap * zxx + am * zx * zx;
    s5 = ap * zyy + am * zy * zy;
}

// ---- LDS jet-matrix access, XOR-swizzled: byte ^= ((sp&7)<<4) ----
__device__ __forceinline__ short8v loadB(const char* baseB, int sp, int k2) {
    return *(const short8v*)(baseB + (((sp << 9) + k2) ^ ((sp & 7) << 4)));
}
__device__ __forceinline__ void storeB(char* baseB, int sp, int jb,
                                       ushort a0, ushort a1, ushort a2, ushort a3) {
    ushort4 v = make_ushort4(a0, a1, a2, a3);
    *(ushort4*)(baseB + (((sp << 9) + (jb << 1)) ^ ((sp & 7) << 4))) = v;
}

// ================= prep: W1..W3 -> bf16 hi/lo in A-fragment order =================
// A-frag for mfma_f32_16x16x32_bf16: lane 16g+r holds A[row r][k = 8g + jj], jj=0..7.
// Amat = W^T (row=j output col, k=input). Frag idx = ((M*8 + kt)*64 + lane), M = j/16.
__global__ __launch_bounds__(256)
void pinn_prep_kernel(const float* __restrict__ W1, const float* __restrict__ W2,
                      const float* __restrict__ W3, ushort* __restrict__ ws) {
    int gid  = blockIdx.x * 256 + threadIdx.x;  // 0..24575
    int l    = gid >> 13;                       // layer 0..2 (8192 threads each)
    int rem  = gid & 8191;
    int M    = rem >> 9;                        // 0..15
    int kt   = (rem >> 6) & 7;                  // 0..7
    int lane = rem & 63;
    const float* W = (l == 0) ? W1 : (l == 1) ? W2 : W3;
    int j  = M * 16 + (lane & 15);
    int k0 = kt * 32 + (lane >> 4) * 8;
    union { ushort u[8]; short8v v; } hi, lo;
    #pragma unroll
    for (int jj = 0; jj < 8; ++jj) {
        float v  = W[(k0 + jj) * 256 + j];      // W[k][j] row-major
        ushort h = f2bf(v);
        hi.u[jj] = h;
        lo.u[jj] = f2bf(v - bf2f(h));
    }
    int off = l * 8192 + ((M * 8 + kt) * 64 + lane);
    ((short8v*)ws)[off]         = hi.v;         // hi frags: [0, 24576)
    ((short8v*)ws)[24576 + off] = lo.v;         // lo frags: [24576, 49152)
}

// ============== main kernel: 16 points / block, 512 threads, 8 waves ==============
// Wave wv owns output cols j in [wv*32, wv*32+32): j-tiles M = wv*2 + m, m in {0,1}.
__global__ __launch_bounds__(512, 4)
void pinn_burger2d_kernel(
    const float* __restrict__ t, const float* __restrict__ x, const float* __restrict__ y,
    const float* __restrict__ W0, const float* __restrict__ b0,
    const float* __restrict__ b1, const float* __restrict__ b2, const float* __restrict__ b3,
    const float* __restrict__ W4, const float* __restrict__ b4,
    const ushort* __restrict__ wf, float* __restrict__ out)
{
    // Jet matrix (B operand, stored as Ajet[sp][k] bf16): hi 96 rows, lo 64 rows (streams 0-3)
    __shared__ ushort BhiS[96 * 256];   // 48 KiB
    __shared__ ushort BloS[64 * 256];   // 32 KiB
    char* bhiB = (char*)BhiS;
    char* bloB = (char*)BloS;

    const int tid  = threadIdx.x;
    const int lane = tid & 63;
    const int wv   = tid >> 6;      // wave 0..7
    const int p    = lane & 15;     // point 0..15
    const int rg   = lane >> 4;     // 0..3
    const int base = blockIdx.x * 16;
    const int gi   = base + p;

    const float tv = t[gi], xv = x[gi], yv = y[gi];

    // ---------------- layer 0: (t,x,y) -> 256 jet, write to LDS ----------------
    #pragma unroll
    for (int m = 0; m < 2; ++m) {
        const int jb = wv * 32 + m * 16 + rg * 4;
        float4 w0t = *(const float4*)(W0 + jb);
        float4 w0x = *(const float4*)(W0 + 256 + jb);
        float4 w0y = *(const float4*)(W0 + 512 + jb);
        float4 bb  = *(const float4*)(b0 + jb);
        float wtA[4] = {w0t.x, w0t.y, w0t.z, w0t.w};
        float wxA[4] = {w0x.x, w0x.y, w0x.z, w0x.w};
        float wyA[4] = {w0y.x, w0y.y, w0y.z, w0y.w};
        float bbA[4] = {bb.x, bb.y, bb.z, bb.w};
        ushort h[6][4]; ushort lo[4][4];
        #pragma unroll
        for (int r = 0; r < 4; ++r) {
            float z = tv * wtA[r] + xv * wxA[r] + yv * wyA[r] + bbA[r];
            float s0, s1, s2, s3, s4, s5;
            jet(z, wtA[r], wxA[r], wyA[r], 0.0f, 0.0f, s0, s1, s2, s3, s4, s5);
            float ss[6] = {s0, s1, s2, s3, s4, s5};
            #pragma unroll
            for (int s = 0; s < 6; ++s) {
                h[s][r] = f2bf(ss[s]);
                if (s < 4) lo[s][r] = f2bf(ss[s] - bf2f(h[s][r]));
            }
        }
        #pragma unroll
        for (int s = 0; s < 6; ++s)
            storeB(bhiB, s * 16 + p, jb, h[s][0], h[s][1], h[s][2], h[s][3]);
        #pragma unroll
        for (int s = 0; s < 4; ++s)
            storeB(bloB, s * 16 + p, jb, lo[s][0], lo[s][1], lo[s][2], lo[s][3]);
    }
    __syncthreads();

    float4v acc[2][6];

    // ---------------- layers 1..3: MFMA  Z^T = W^T · Ajet^T ----------------
    for (int li = 0; li < 3; ++li) {
        #pragma unroll
        for (int m = 0; m < 2; ++m)
            #pragma unroll
            for (int n = 0; n < 6; ++n) {
                float4v z4 = {0.0f, 0.0f, 0.0f, 0.0f};
                acc[m][n] = z4;
            }

        const short8v* whf = (const short8v*)wf + li * 8192;
        const short8v* wlf = (const short8v*)wf + 24576 + li * 8192;

        for (int kt = 0; kt < 8; ++kt) {
            short8v bh[6], bl[4];
            const int k2 = kt * 64 + rg * 16;
            #pragma unroll
            for (int n = 0; n < 6; ++n) bh[n] = loadB(bhiB, n * 16 + p, k2);
            #pragma unroll
            for (int n = 0; n < 4; ++n) bl[n] = loadB(bloB, n * 16 + p, k2);
            #pragma unroll
            for (int m = 0; m < 2; ++m) {
                const int fi = (((wv * 2 + m) * 8 + kt) * 64) + lane;
                short8v wh = whf[fi];
                short8v wl = wlf[fi];
                #pragma unroll
                for (int n = 0; n < 6; ++n)
                    acc[m][n] = __builtin_amdgcn_mfma_f32_16x16x32_bf16(wh, bh[n], acc[m][n], 0, 0, 0);
                #pragma unroll
                for (int n = 0; n < 4; ++n)
                    acc[m][n] = __builtin_amdgcn_mfma_f32_16x16x32_bf16(wl, bh[n], acc[m][n], 0, 0, 0);
                #pragma unroll
                for (int n = 0; n < 4; ++n)
                    acc[m][n] = __builtin_amdgcn_mfma_f32_16x16x32_bf16(wh, bl[n], acc[m][n], 0, 0, 0);
            }
        }
        __syncthreads();   // all waves done reading B before overwrite / reuse

        if (li < 2) {
            const float* bL = (li == 0) ? b1 : b2;
            #pragma unroll
            for (int m = 0; m < 2; ++m) {
                const int jb = wv * 32 + m * 16 + rg * 4;
                float4 bb = *(const float4*)(bL + jb);
                float bbA[4] = {bb.x, bb.y, bb.z, bb.w};
                ushort h[6][4]; ushort lo[4][4];
                #pragma unroll
                for (int r = 0; r < 4; ++r) {
                    float z   = acc[m][0][r] + bbA[r];
                    float s0, s1, s2, s3, s4, s5;
                    jet(z, acc[m][1][r], acc[m][2][r], acc[m][3][r],
                        acc[m][4][r], acc[m][5][r], s0, s1, s2, s3, s4, s5);
                    float ss[6] = {s0, s1, s2, s3, s4, s5};
                    #pragma unroll
                    for (int s = 0; s < 6; ++s) {
                        h[s][r] = f2bf(ss[s]);
                        if (s < 4) lo[s][r] = f2bf(ss[s] - bf2f(h[s][r]));
                    }
                }
                #pragma unroll
                for (int s = 0; s < 6; ++s)
                    storeB(bhiB, s * 16 + p, jb, h[s][0], h[s][1], h[s][2], h[s][3]);
                #pragma unroll
                for (int s = 0; s < 4; ++s)
                    storeB(bloB, s * 16 + p, jb, lo[s][0], lo[s][1], lo[s][2], lo[s][3]);
            }
            __syncthreads();
        }
    }

    // ---------------- layer-3 jet (registers) + final 256->1 dot ----------------
    float part[6] = {0, 0, 0, 0, 0, 0};
    #pragma unroll
    for (int m = 0; m < 2; ++m) {
        const int jb = wv * 32 + m * 16 + rg * 4;
        float4 bb = *(const float4*)(b3 + jb);
        float4 w4 = *(const float4*)(W4 + jb);
        float bbA[4] = {bb.x, bb.y, bb.z, bb.w};
        float w4A[4] = {w4.x, w4.y, w4.z, w4.w};
        #pragma unroll
        for (int r = 0; r < 4; ++r) {
            float z = acc[m][0][r] + bbA[r];
            float s0, s1, s2, s3, s4, s5;
            jet(z, acc[m][1][r], acc[m][2][r], acc[m][3][r],
                acc[m][4][r], acc[m][5][r], s0, s1, s2, s3, s4, s5);
            part[0] += s0 * w4A[r];
            part[1] += s1 * w4A[r];
            part[2] += s2 * w4A[r];
            part[3] += s3 * w4A[r];
            part[4] += s4 * w4A[r];
            part[5] += s5 * w4A[r];
        }
    }
    // reduce over the 4 lanes sharing a point (lane, lane^16, lane^32, lane^48)
    #pragma unroll
    for (int s = 0; s < 6; ++s) {
        part[s] += __shfl_xor(part[s], 16, 64);
        part[s] += __shfl_xor(part[s], 32, 64);
    }
    float* resf = (float*)BloS;   // overlay (Blo no longer needed; barrier above protects)
    if (lane < 16) {
        #pragma unroll
        for (int s = 0; s < 6; ++s) resf[(wv * 6 + s) * 16 + p] = part[s];
    }
    __syncthreads();

    if (tid < 16) {
        const int pp = tid;
        const int g  = base + pp;
        float u = b4[0], ut = 0, ux = 0, uy = 0, uxx = 0, uyy = 0;
        #pragma unroll
        for (int w = 0; w < 8; ++w) {
            u   += resf[(w * 6 + 0) * 16 + pp];
            ut  += resf[(w * 6 + 1) * 16 + pp];
            ux  += resf[(w * 6 + 2) * 16 + pp];
            uy  += resf[(w * 6 + 3) * 16 + pp];
            uxx += resf[(w * 6 + 4) * 16 + pp];
            uyy += resf[(w * 6 + 5) * 16 + pp];
        }
        out[g]        = u;
        out[NPTS + g] = ut + u * ux + u * uy - NU_F * (uxx + uyy);
    }
}

extern "C" void kernel_launch(void* const* d_in, const int* in_sizes, int n_in,
                              void* d_out, int out_size, void* d_ws, size_t ws_size,
                              hipStream_t stream) {
    const float* t  = (const float*)d_in[0];
    const float* x  = (const float*)d_in[1];
    const float* y  = (const float*)d_in[2];
    const float* W0 = (const float*)d_in[3];
    const float* b0 = (const float*)d_in[4];
    const float* W1 = (const float*)d_in[5];
    const float* b1 = (const float*)d_in[6];
    const float* W2 = (const float*)d_in[7];
    const float* b2 = (const float*)d_in[8];
    const float* W3 = (const float*)d_in[9];
    const float* b3 = (const float*)d_in[10];
    const float* W4 = (const float*)d_in[11];
    const float* b4 = (const float*)d_in[12];
    float* out = (float*)d_out;

    pinn_prep_kernel<<<96, 256, 0, stream>>>(W1, W2, W3, (ushort*)d_ws);
    pinn_burger2d_kernel<<<NPTS / 16, 512, 0, stream>>>(
        t, x, y, W0, b0, b1, b2, b3, W4, b4, (const ushort*)d_ws, out);
}